// Round 4
// baseline (8242.309 us; speedup 1.0000x reference)
//
#include <hip/hip_runtime.h>
#include <math.h>

// ---- problem sizes ----
// BS=16, T=48, N=147, IN=294, H=128, AH=8(dh=16), GH=4, DFF=2048, B2=BS*T=768

typedef _Float16 half8 __attribute__((ext_vector_type(8)));
typedef _Float16 half4 __attribute__((ext_vector_type(4)));
typedef _Float16 half2v __attribute__((ext_vector_type(2)));
typedef float f32x4 __attribute__((ext_vector_type(4)));

#if __has_builtin(__builtin_amdgcn_fdot2)
#define DOT2(a,b,c) __builtin_amdgcn_fdot2((a),(b),(c),false)
#else
#define DOT2(a,b,c) ((c) + (float)(a)[0]*(float)(b)[0] + (float)(a)[1]*(float)(b)[1])
#endif

// ---- workspace float offsets ----
// Phase-A buffers alias the Zf region (all dead before Zf is written in k13).
static constexpr size_t Y0o   = 0;         //  98304  [768][128] f32
static constexpr size_t QKVo  = 98304;     // 294912  [768][384] f32
static constexpr size_t ATTOo = 393216;    //  98304
static constexpr size_t Y1o   = 491520;    //  98304  f32 (residual for k6b)
static constexpr size_t Y1Ho  = 589824;    //  49152  fp16 [768][128]
static constexpr size_t FFHo  = 638976;    // 786432  fp16 [768][2048]
static constexpr size_t PREo  = 1425408;   //  98304  f32 [768][128]
static constexpr size_t Y2Ho  = 1523712;   //  49152  fp16 [768][128]
static constexpr size_t XW1o  = 1572864;   // 903168  f32 [768][1176]
static constexpr size_t Y3o   = 2476032;   // 225792  f32 [768][294] (ends 2701824)
static constexpr size_t Zo    = 0;         // fp16 [768][18816] = 7225344 floats (aliases phase A)
static constexpr size_t So    = 7225344;   // 903168  [768][4][147][2]
static constexpr size_t G12o  = 8128512;   // 225792  [768][147][2]
static constexpr size_t WHOo  = 8354304;   // fp16 [768][147][128] = 7225344 floats
static constexpr size_t WFo   = 15579648;  // fp16 [512][18816] = 4816896
static constexpr size_t ZGPo  = 20396544;  // f32 [12][768][512] = 4718592
static constexpr size_t ZGo   = 25115136;  // 393216 [768][512]
static constexpr size_t HTo   = 25508352;  //   2048 [16][128]
static constexpr size_t C12o  = 25510400;  //     16
static constexpr size_t WT1Ho = 25510416;  // fp16 [37][1176][8] = 174048 floats
static constexpr size_t WT2Ho = 25684464;  // fp16 [16][512][8]  = 32768
static constexpr size_t FF1Ho = 25717232;  // fp16 [2048][128] = 131072
static constexpr size_t FF2Ho = 25848304;  // fp16 [128][2048] = 131072
static constexpr size_t WIH1Ho= 25979376;  // fp16 [1216][128] = 77824 (rows>=1176 zero)
static constexpr size_t W2To  = 26057200;  // fp16 [128][512] = 32768
static constexpr size_t EINTo = 26089968;  //  49152 [128][384] f32
static constexpr size_t EOUTTo= 26139120;  //  16384 [128][128] f32
static constexpr size_t WTRTo = 26155504;  //  37632 [294][128] f32
static constexpr size_t MASKo = 26193136;  //  u64[441] (896 floats reserved)
// total extent: 26,194,032 floats = 99.9 MiB

__device__ __forceinline__ float eluf(float x){ return x > 0.f ? x : expm1f(x); }
__device__ __forceinline__ float sigf(float x){ return 1.f/(1.f+expf(-x)); }

// ---------- weight transposes / fp16 packs ----------
__global__ void k_prep(const float* Whh1, const float* Whh2, const float* ff1w,
                       const float* ff2w, const float* Wih1, const float* einw,
                       const float* eoutw, const float* wtr, const float* gw2, float* ws) {
  int id = blockIdx.x * 256 + threadIdx.x;
  if (id < 348096) { // WT1H fp16 [37 kg][1176 j][8 k]
    int e=id&7, r=id>>3; int j=r%1176, gi=r/1176; int k=gi*8+e;
    ((_Float16*)(ws+WT1Ho))[id] = (_Float16)((k<294)? Whh1[j*294+k] : 0.f); return; }
  id -= 348096;
  if (id < 65536) { // WT2H fp16 [16][512][8]
    int e=id&7, r=id>>3; int j=r&511, gi=r>>9; int k=gi*8+e;
    ((_Float16*)(ws+WT2Ho))[id] = (_Float16)Whh2[j*128+k]; return; }
  id -= 65536;
  if (id < 262144) { ((_Float16*)(ws+FF1Ho))[id] = (_Float16)ff1w[id]; return; }
  id -= 262144;
  if (id < 262144) { ((_Float16*)(ws+FF2Ho))[id] = (_Float16)ff2w[id]; return; }
  id -= 262144;
  if (id < 155648) { int j=id>>7, k=id&127;
    ((_Float16*)(ws+WIH1Ho))[id] = (_Float16)((j<1176)? Wih1[j*128+k] : 0.f); return; }
  id -= 155648;
  if (id < 65536)  { int h=id>>9, q=id&511;
    ((_Float16*)(ws+W2To))[id] = (_Float16)gw2[q*128+h]; return; }
  id -= 65536;
  if (id < 49152)  { int k=id/384,  j=id-k*384;  ws[EINTo+id] = einw[j*128+k]; return; }
  id -= 49152;
  if (id < 16384)  { int k=id/128,  j=id-k*128;  ws[EOUTTo+id]= eoutw[j*128+k]; return; }
  id -= 16384;
  if (id < 37632)  { int k=id/128,  j=id-k*128;  ws[WTRTo+id] = wtr[j*294+k]; return; }
}

// ---------- GAT scalar precompute + adjacency bitmask ----------
__global__ void k_c12_mask(const float* gw1, const float* ga1, const int* adj, float* ws) {
  int tid = threadIdx.x;
  if (tid < 8) {
    int k = tid>>1, c = tid&1;
    float a=0.f, b=0.f;
    for (int h=0; h<128; ++h) {
      float w = gw1[(k*2+c)*128+h];
      a += w * ga1[k*256+h];
      b += w * ga1[k*256+128+h];
    }
    ws[C12o+tid] = a; ws[C12o+8+tid] = b;
  }
  unsigned long long* msk = (unsigned long long*)(ws + MASKo);
  for (int i = tid; i < 441; i += 64) {
    int r = i/3, w = i-r*3;
    unsigned long long b = 0ull;
    for (int bit=0; bit<64; ++bit) {
      int j = w*64+bit;
      if (j < 147 && adj[r*147+j] > 0) b |= (1ull<<bit);
    }
    msk[i] = b;
  }
}

// ---------- input projection + ELU ----------
__global__ void k1_trans(const float* X, const float* btr, float* ws) {
  int row = blockIdx.x, tid = threadIdx.x; // 128 thr
  __shared__ float xr[294];
  for (int i=tid; i<294; i+=128) xr[i] = X[row*294+i];
  __syncthreads();
  float acc = btr[tid];
  const float* w = ws + WTRTo;
  for (int k=0;k<294;++k) acc += xr[k]*w[k*128+tid];
  ws[Y0o + (size_t)row*128 + tid] = eluf(acc);
}

// ---------- QKV projection ----------
__global__ void k2_qkv(const float* einb, float* ws) {
  int row = blockIdx.x, tid = threadIdx.x; // 384 thr
  __shared__ float yr[128];
  if (tid<128) yr[tid] = ws[Y0o+(size_t)row*128+tid];
  __syncthreads();
  float acc = einb[tid];
  const float* w = ws + EINTo;
  for (int k=0;k<128;++k) acc += yr[k]*w[k*384+tid];
  ws[QKVo + (size_t)row*384 + tid] = acc;
}

// ---------- MHA core ----------
__global__ void k3_attn(float* ws) {
  int bid = blockIdx.x; int bs = bid>>3, a = bid&7; int tid = threadIdx.x; // 256 thr
  __shared__ float q[48][16], kk[48][16], v[48][16], sc[48][49];
  for (int idx=tid; idx<768; idx+=256) {
    int t = idx>>4, d = idx&15;
    const float* base = ws + QKVo + (size_t)(bs*48+t)*384 + a*16 + d;
    q[t][d] = base[0]; kk[t][d] = base[128]; v[t][d] = base[256];
  }
  __syncthreads();
  for (int idx=tid; idx<2304; idx+=256) {
    int i = idx/48, j = idx-i*48;
    float s = 0.f;
    for (int d=0;d<16;++d) s += q[i][d]*kk[j][d];
    sc[i][j] = s*0.25f;
  }
  __syncthreads();
  if (tid < 48) {
    float mx = -INFINITY;
    for (int j=0;j<48;++j) mx = fmaxf(mx, sc[tid][j]);
    float s = 0.f;
    for (int j=0;j<48;++j){ float p = expf(sc[tid][j]-mx); sc[tid][j]=p; s+=p; }
    float inv = 1.f/s;
    for (int j=0;j<48;++j) sc[tid][j]*=inv;
  }
  __syncthreads();
  for (int idx=tid; idx<768; idx+=256) {
    int t = idx>>4, d = idx&15;
    float s=0.f;
    for (int j=0;j<48;++j) s += sc[t][j]*v[j][d];
    ws[ATTOo + (size_t)(bs*48+t)*128 + a*16 + d] = s;
  }
}

// ---------- attn out-proj + residual + LN1 (stores f32 + fp16) ----------
__global__ void k4_ln1(const float* eoutb, const float* g, const float* b, float* ws) {
  int row = blockIdx.x, tid = threadIdx.x; // 128 thr
  __shared__ float orow[128];
  __shared__ float red[128];
  __shared__ float mv[2];
  orow[tid] = ws[ATTOo+(size_t)row*128+tid];
  __syncthreads();
  float acc = eoutb[tid] + ws[Y0o+(size_t)row*128+tid];
  const float* w = ws + EOUTTo;
  for (int k=0;k<128;++k) acc += orow[k]*w[k*128+tid];
  red[tid]=acc; __syncthreads();
  for (int s=64;s>0;s>>=1){ if(tid<s) red[tid]+=red[tid+s]; __syncthreads(); }
  if (tid==0) mv[0]=red[0]*(1.f/128.f);
  __syncthreads();
  float d = acc - mv[0];
  red[tid]=d*d; __syncthreads();
  for (int s=64;s>0;s>>=1){ if(tid<s) red[tid]+=red[tid+s]; __syncthreads(); }
  if (tid==0) mv[1]=red[0]*(1.f/128.f);
  __syncthreads();
  float val = d*rsqrtf(mv[1]+1e-5f)*g[tid]+b[tid];
  ws[Y1o+(size_t)row*128+tid] = val;
  ((_Float16*)(ws+Y1Ho))[(size_t)row*128+tid] = (_Float16)val;
}

// ---------- FFN1 MFMA: FFH = relu(Y1 @ ff1w^T + b1), fp16 out ----------
__global__ void __launch_bounds__(256) k5g(const float* b1, float* ws) {
  int tid=threadIdx.x; int gw=blockIdx.x*4+(tid>>6);
  int l=tid&63, lr=l&15, kg=l>>4;
  int mt=gw>>5, nt=gw&31;
  const _Float16* A=(const _Float16*)(ws+Y1Ho);
  const _Float16* B=(const _Float16*)(ws+FF1Ho);
  _Float16* C=(_Float16*)(ws+FFHo);
  size_t r0=(size_t)mt*64, c0=(size_t)nt*64;
  f32x4 acc[4][4];
  #pragma unroll
  for(int a=0;a<4;++a)
    #pragma unroll
    for(int b=0;b<4;++b) acc[a][b]=(f32x4){0.f,0.f,0.f,0.f};
  #pragma unroll
  for (int s=0;s<4;++s){
    int kb=s*32+kg*8;
    half8 av[4], bv[4];
    #pragma unroll
    for(int f=0;f<4;++f) av[f]=*(const half8*)(A+(r0+f*16+lr)*128+kb);
    #pragma unroll
    for(int f=0;f<4;++f) bv[f]=*(const half8*)(B+(c0+f*16+lr)*128+kb);
    #pragma unroll
    for(int fr=0;fr<4;++fr)
      #pragma unroll
      for(int fc=0;fc<4;++fc)
        acc[fr][fc]=__builtin_amdgcn_mfma_f32_16x16x32_f16(av[fr],bv[fc],acc[fr][fc],0,0,0);
  }
  #pragma unroll
  for(int fr=0;fr<4;++fr)
    #pragma unroll
    for(int fc=0;fc<4;++fc){
      size_t col=c0+fc*16+lr;
      float bb=b1[col];
      #pragma unroll
      for(int r=0;r<4;++r){
        float v=acc[fr][fc][r]+bb; v=fmaxf(v,0.f);
        C[(r0+fr*16+kg*4+r)*2048+col]=(_Float16)v;
      }
    }
}

// ---------- FFN2 MFMA: PRE = FFH @ ff2w^T + b2 (f32 out) ----------
__global__ void __launch_bounds__(256) k6g(const float* b2, float* ws) {
  int tid=threadIdx.x; int gw=blockIdx.x*4+(tid>>6);
  int l=tid&63, lr=l&15, kg=l>>4;
  int mt=gw>>1, nt=gw&1;
  const _Float16* A=(const _Float16*)(ws+FFHo);
  const _Float16* B=(const _Float16*)(ws+FF2Ho);
  float* C=ws+PREo;
  size_t r0=(size_t)mt*64, c0=(size_t)nt*64;
  f32x4 acc[4][4];
  #pragma unroll
  for(int a=0;a<4;++a)
    #pragma unroll
    for(int b=0;b<4;++b) acc[a][b]=(f32x4){0.f,0.f,0.f,0.f};
  for (int s=0;s<64;++s){
    int kb=s*32+kg*8;
    half8 av[4], bv[4];
    #pragma unroll
    for(int f=0;f<4;++f) av[f]=*(const half8*)(A+(r0+f*16+lr)*2048+kb);
    #pragma unroll
    for(int f=0;f<4;++f) bv[f]=*(const half8*)(B+(c0+f*16+lr)*2048+kb);
    #pragma unroll
    for(int fr=0;fr<4;++fr)
      #pragma unroll
      for(int fc=0;fc<4;++fc)
        acc[fr][fc]=__builtin_amdgcn_mfma_f32_16x16x32_f16(av[fr],bv[fc],acc[fr][fc],0,0,0);
  }
  #pragma unroll
  for(int fr=0;fr<4;++fr)
    #pragma unroll
    for(int fc=0;fc<4;++fc){
      size_t col=c0+fc*16+lr;
      float bb=b2[col];
      #pragma unroll
      for(int r=0;r<4;++r)
        C[(r0+fr*16+kg*4+r)*128+col]=acc[fr][fc][r]+bb;
    }
}

// ---------- LN2: Y2H = LN(Y1 + PRE) fp16 ----------
__global__ void k6b_ln2(const float* g, const float* b, float* ws) {
  int row=blockIdx.x, tid=threadIdx.x; // 128 thr
  __shared__ float red[128];
  __shared__ float mv[2];
  float acc = ws[PREo+(size_t)row*128+tid] + ws[Y1o+(size_t)row*128+tid];
  red[tid]=acc; __syncthreads();
  for (int s=64;s>0;s>>=1){ if(tid<s) red[tid]+=red[tid+s]; __syncthreads(); }
  if (tid==0) mv[0]=red[0]*(1.f/128.f);
  __syncthreads();
  float d = acc - mv[0];
  red[tid]=d*d; __syncthreads();
  for (int s=64;s>0;s>>=1){ if(tid<s) red[tid]+=red[tid+s]; __syncthreads(); }
  if (tid==0) mv[1]=red[0]*(1.f/128.f);
  __syncthreads();
  float val = d*rsqrtf(mv[1]+1e-5f)*g[tid]+b[tid];
  ((_Float16*)(ws+Y2Ho))[(size_t)row*128+tid] = (_Float16)val;
}

// ---------- LSTM1 input proj MFMA: XW1 = Y2 @ Wih1^T + biases (f32) ----------
__global__ void __launch_bounds__(256) k7g(const float* bih1, const float* bhh1, float* ws) {
  int tid=threadIdx.x; int gw=blockIdx.x*4+(tid>>6);
  int l=tid&63, lr=l&15, kg=l>>4;
  int mt=gw/19, nt=gw-mt*19;
  const _Float16* A=(const _Float16*)(ws+Y2Ho);
  const _Float16* B=(const _Float16*)(ws+WIH1Ho);
  float* C=ws+XW1o;
  size_t r0=(size_t)mt*64, c0=(size_t)nt*64;
  f32x4 acc[4][4];
  #pragma unroll
  for(int a=0;a<4;++a)
    #pragma unroll
    for(int b=0;b<4;++b) acc[a][b]=(f32x4){0.f,0.f,0.f,0.f};
  #pragma unroll
  for (int s=0;s<4;++s){
    int kb=s*32+kg*8;
    half8 av[4], bv[4];
    #pragma unroll
    for(int f=0;f<4;++f) av[f]=*(const half8*)(A+(r0+f*16+lr)*128+kb);
    #pragma unroll
    for(int f=0;f<4;++f) bv[f]=*(const half8*)(B+(c0+f*16+lr)*128+kb);
    #pragma unroll
    for(int fr=0;fr<4;++fr)
      #pragma unroll
      for(int fc=0;fc<4;++fc)
        acc[fr][fc]=__builtin_amdgcn_mfma_f32_16x16x32_f16(av[fr],bv[fc],acc[fr][fc],0,0,0);
  }
  #pragma unroll
  for(int fr=0;fr<4;++fr)
    #pragma unroll
    for(int fc=0;fc<4;++fc){
      size_t col=c0+fc*16+lr;
      if (col<1176){
        float bb=bih1[col]+bhh1[col];
        #pragma unroll
        for(int r=0;r<4;++r)
          C[(r0+fr*16+kg*4+r)*1176+col]=acc[fr][fc][r]+bb;
      }
    }
}

// ---------- LSTM1 recurrence: fp16 weights, packed dot2 ----------
__global__ void __launch_bounds__(1024) k8_lstm1(float* ws) {
  int b = blockIdx.x, tid = threadIdx.x; // 1024 thr
  __shared__ __align__(16) _Float16 hs[296];
  __shared__ float cc[294], g[1176];
  if (tid < 296) hs[tid] = (_Float16)0.f;
  if (tid < 294) cc[tid] = 0.f;
  const _Float16* wt = (const _Float16*)(ws + WT1Ho); // [37][1176][8]
  for (int t=0;t<48;++t) {
    __syncthreads();
    int row = b*48+t;
    for (int jj=tid; jj<1176; jj+=1024) {
      float acc = ws[XW1o+(size_t)row*1176+jj];
      for (int gi=0; gi<37; ++gi) {
        half8 w = *(const half8*)&wt[(gi*1176+jj)*8];
        const half2v* hp = (const half2v*)&hs[gi*8];
        #pragma unroll
        for (int p=0;p<4;++p) {
          half2v wp = {w[2*p], w[2*p+1]};
          acc = DOT2(wp, hp[p], acc);
        }
      }
      g[jj]=acc;
    }
    __syncthreads();
    if (tid<294) {
      float ii=sigf(g[tid]);
      float ff=sigf(g[294+tid]);
      float gg=tanhf(g[588+tid]);
      float oo=sigf(g[882+tid]);
      float cn = ff*cc[tid]+ii*gg;
      cc[tid]=cn;
      float hn = oo*tanhf(cn);
      hs[tid] = (_Float16)hn;
      ws[Y3o+(size_t)row*294+tid]=hn;
    }
  }
}

// ---------- GAT layer 1: masked softmax + rank-2 aggregation ----------
__global__ void k10_gat1(float* ws) {
  int bid=blockIdx.x; int m=bid>>2, k=bid&3; int tid=threadIdx.x; // 192 thr
  __shared__ float x0[147],x1[147],f1[147],f2[147];
  __shared__ unsigned long long msk[441];
  for (int i=tid;i<294;i+=192){
    int n=i>>1,cc=i&1;
    float v=ws[Y3o + (size_t)n*1536 + m*2 + cc];
    if(cc==0)x0[n]=v; else x1[n]=v;
  }
  const unsigned long long* gm = (const unsigned long long*)(ws+MASKo);
  for (int i=tid;i<441;i+=192) msk[i]=gm[i];
  __syncthreads();
  float c10=ws[C12o+k*2], c11=ws[C12o+k*2+1], c20=ws[C12o+8+k*2], c21=ws[C12o+8+k*2+1];
  for (int i=tid;i<147;i+=192){ f1[i]=x0[i]*c10+x1[i]*c11; f2[i]=x0[i]*c20+x1[i]*c21; }
  __syncthreads();
  for (int i=tid;i<147;i+=192) {
    float fi=f1[i];
    float mx=-INFINITY;
    for (int j=0;j<147;++j){
      float e=fi+f2[j]; e = e>0.f?e:0.1f*e;
      bool mk = (msk[i*3+(j>>6)]>>(j&63))&1ull;
      mx = fmaxf(mx, mk? e : -9e15f);
    }
    float s=0.f,a0=0.f,a1=0.f;
    for (int j=0;j<147;++j){
      float e=fi+f2[j]; e = e>0.f?e:0.1f*e;
      bool mk=(msk[i*3+(j>>6)]>>(j&63))&1ull;
      float p = expf((mk? e: -9e15f)-mx);
      s+=p; a0+=p*x0[j]; a1+=p*x1[j];
    }
    float inv=1.f/s;
    size_t o = So + ((size_t)(m*4+k)*147+i)*2;
    ws[o]=a0*inv; ws[o+1]=a1*inv;
  }
}

// ---------- GAT layer 2 GEMM (MFMA) + fused g1/g2: Who(fp16) = elu(h1) @ W2 ----------
__global__ void __launch_bounds__(256) k11_who(const float* gw1, const float* ga2, float* ws) {
  int m=blockIdx.x, tid=threadIdx.x;
  int w=tid>>6, l=tid&63, lr=l&15, kg=l>>4;
  __shared__ float s0s[4][148], s1s[4][148];
  __shared__ float w1s[1024];
  __shared__ float a2s[256];
  __shared__ _Float16 h1t[160*32];
  __shared__ float g1s[160], g2s[160];
  for (int idx=tid; idx<588; idx+=256){
    int k=idx/147, i=idx-k*147;
    size_t o=So+((size_t)(m*4+k)*147+i)*2; s0s[k][i]=ws[o]; s1s[k][i]=ws[o+1];
  }
  for (int idx=tid; idx<1024; idx+=256) w1s[idx]=gw1[idx];
  for (int idx=tid; idx<256; idx+=256) a2s[idx]=ga2[idx];
  if (tid<160){ g1s[tid]=0.f; g2s[tid]=0.f; }
  f32x4 acc[10][2];
  #pragma unroll
  for(int a=0;a<10;++a){ acc[a][0]=(f32x4){0.f,0.f,0.f,0.f}; acc[a][1]=(f32x4){0.f,0.f,0.f,0.f}; }
  const _Float16* W2T = (const _Float16*)(ws+W2To);
  for (int q0=0;q0<512;q0+=32){
    __syncthreads();
    for (int idx=tid; idx<5120; idx+=256){
      int i=idx>>5, kk=idx&31;
      _Float16 hv=(_Float16)0.f;
      if (i<147){
        int q=q0+kk, k=q>>7, hp=q&127;
        float v=s0s[k][i]*w1s[k*256+hp]+s1s[k][i]*w1s[k*256+128+hp];
        hv=(_Float16)eluf(v);
      }
      h1t[idx]=hv;
    }
    __syncthreads();
    half8 bv0=*(const half8*)(W2T+(size_t)(w*32+lr)*512+q0+kg*8);
    half8 bv1=*(const half8*)(W2T+(size_t)(w*32+16+lr)*512+q0+kg*8);
    #pragma unroll
    for (int rf=0;rf<10;++rf){
      half8 av=*(const half8*)&h1t[(rf*16+lr)*32+kg*8];
      acc[rf][0]=__builtin_amdgcn_mfma_f32_16x16x32_f16(av,bv0,acc[rf][0],0,0,0);
      acc[rf][1]=__builtin_amdgcn_mfma_f32_16x16x32_f16(av,bv1,acc[rf][1],0,0,0);
    }
  }
  _Float16* whoH=(_Float16*)(ws+WHOo);
  #pragma unroll
  for (int rf=0;rf<10;++rf)
    #pragma unroll
    for (int cf=0;cf<2;++cf)
      #pragma unroll
      for (int r=0;r<4;++r){
        int row=rf*16+kg*4+r;
        int col=w*32+cf*16+lr;
        float v=acc[rf][cf][r];
        bool ok=row<147;
        if (ok) whoH[((size_t)m*147+row)*128+col]=(_Float16)v;
        float p1=ok? v*a2s[col]:0.f;
        float p2=ok? v*a2s[128+col]:0.f;
        p1+=__shfl_xor(p1,1); p1+=__shfl_xor(p1,2); p1+=__shfl_xor(p1,4); p1+=__shfl_xor(p1,8);
        p2+=__shfl_xor(p2,1); p2+=__shfl_xor(p2,2); p2+=__shfl_xor(p2,4); p2+=__shfl_xor(p2,8);
        if (ok && lr==0){ atomicAdd(&g1s[row],p1); atomicAdd(&g2s[row],p2); }
      }
  __syncthreads();
  for (int i=tid;i<147;i+=256){
    ws[G12o+((size_t)m*147+i)*2]=g1s[i];
    ws[G12o+((size_t)m*147+i)*2+1]=g2s[i];
  }
}

// ---------- GAT layer 2: softmax + PV + elu + sc shortcut + scatter to Zf (fp16) ----------
// acc kept STRICTLY in registers (f32x4, all loops unrolled, static indices)
__global__ void k13_gat2(const float* X, const float* Wsc, const float* bsc, float* ws) {
  int m=blockIdx.x, tid=threadIdx.x; // 256 thr
  int tx=tid&15, ty=tid>>4;
  __shared__ float att[80][148];
  __shared__ float bch[16][128];
  __shared__ float g1s[147], g2s[147];
  __shared__ float wscs[256], bscs[128];
  __shared__ unsigned long long msk[441];
  _Float16* zf = (_Float16*)(ws + Zo);
  const _Float16* whoH=(const _Float16*)(ws+WHOo);
  for (int i=tid;i<147;i+=256){ size_t o=G12o+((size_t)m*147+i)*2; g1s[i]=ws[o]; g2s[i]=ws[o+1]; }
  wscs[tid]=Wsc[tid];
  if (tid<128) bscs[tid]=bsc[tid];
  const unsigned long long* gm=(const unsigned long long*)(ws+MASKo);
  for (int i=tid;i<441;i+=256) msk[i]=gm[i];
  __syncthreads();
  for (int p=0;p<2;++p) {
    int i0=p*74, cnt = p?73:74;
    for (int r=tid;r<cnt;r+=256) {
      int i=i0+r; float gi=g1s[i];
      float mx=-INFINITY;
      for (int j=0;j<147;++j){
        float e=gi+g2s[j]; e=e>0.f?e:0.1f*e;
        bool mk=(msk[i*3+(j>>6)]>>(j&63))&1ull;
        mx=fmaxf(mx, mk?e:-9e15f);
      }
      float s=0.f;
      for (int j=0;j<147;++j){
        float e=gi+g2s[j]; e=e>0.f?e:0.1f*e;
        bool mk=(msk[i*3+(j>>6)]>>(j&63))&1ull;
        float pp=expf((mk?e:-9e15f)-mx);
        att[r][j]=pp; s+=pp;
      }
      float inv=1.f/s;
      for (int j=0;j<147;++j) att[r][j]*=inv;
    }
    __syncthreads();
    f32x4 acc0[5], acc1[5];
    #pragma unroll
    for (int r=0;r<5;++r){ acc0[r]=(f32x4){0.f,0.f,0.f,0.f}; acc1[r]=(f32x4){0.f,0.f,0.f,0.f}; }
    for (int qc=0;qc<147;qc+=16) {
      int qn = (147-qc)<16 ? (147-qc) : 16;
      for (int idx=tid; idx<qn*128; idx+=256){
        int qq=idx>>7, hp=idx&127;
        bch[qq][hp]=(float)whoH[((size_t)m*147+qc+qq)*128+hp];
      }
      __syncthreads();
      for (int qq=0;qq<qn;++qq){
        f32x4 b0=*(const f32x4*)&bch[qq][tx*8];
        f32x4 b1=*(const f32x4*)&bch[qq][tx*8+4];
        #pragma unroll
        for (int r=0;r<5;++r){
          float a=att[ty+16*r][qc+qq];
          f32x4 as={a,a,a,a};
          acc0[r]+=as*b0; acc1[r]+=as*b1;
        }
      }
      __syncthreads();
    }
    #pragma unroll
    for (int r=0;r<5;++r){
      int lrw=ty+16*r;
      if (lrw<cnt){
        int i=i0+lrw;
        int gidx = i*98304 + m*128 + tx*8;
        int bs = gidx/903168; int r2 = gidx-bs*903168;
        int t = r2/18816; int q = r2-t*18816;
        int nn=q>>7;
        const float* xr = X + (size_t)(bs*48+t)*294 + nn*2;
        float x0=xr[0], x1=xr[1];
        half8 hv;
        #pragma unroll
        for (int c=0;c<8;++c){
          int hh=tx*8+c;
          float av = (c<4)? acc0[r][c] : acc1[r][c-4];
          float sv = x0*wscs[hh*2] + x1*wscs[hh*2+1] + bscs[hh];
          hv[c]=(_Float16)(eluf(av) + eluf(sv));
        }
        *(half8*)&zf[(size_t)(bs*48+t)*18816 + q] = hv;
      }
    }
    __syncthreads();
  }
}

// ---------- Wih2 -> fp16 ----------
__global__ void kWconv(const float* Wih2, float* ws) {
  size_t i = ((size_t)blockIdx.x*256 + threadIdx.x)*4;
  _Float16* wf = (_Float16*)(ws + WFo);
  float4 v = *(const float4*)&Wih2[i];
  half4 h = {(_Float16)v.x, (_Float16)v.y, (_Float16)v.z, (_Float16)v.w};
  *(half4*)&wf[i] = h;
}

// ---------- Zg = Zf @ WfT : fp16 MFMA, per-wave 64x64 tiles, split-K=12 ----------
__global__ void __launch_bounds__(256) k14_mfma(float* ws) {
  const int tid = threadIdx.x;
  const int gw = blockIdx.x*4 + (tid>>6);     // global wave id, 0..1151
  const int l = tid & 63, lr = l & 15, kg = l >> 4;
  const int ks = gw / 96;                      // K-split 0..11
  const int tile = gw - ks*96;
  const int mt = tile >> 3, nt = tile & 7;     // 12 x 8 tiles of 64x64
  const size_t r0 = (size_t)mt*64, c0 = (size_t)nt*64;
  const _Float16* A = (const _Float16*)(ws + Zo);   // [768][18816]
  const _Float16* B = (const _Float16*)(ws + WFo);  // [512][18816]
  f32x4 acc[4][4];
  #pragma unroll
  for (int a=0;a<4;++a)
    #pragma unroll
    for (int b=0;b<4;++b) acc[a][b] = (f32x4){0.f,0.f,0.f,0.f};
  size_t kb = (size_t)ks*1568 + kg*8;
  for (int s=0; s<49; ++s) {
    half8 av[4], bv[4];
    #pragma unroll
    for (int f=0; f<4; ++f) av[f] = *(const half8*)(A + (r0+f*16+lr)*18816 + kb);
    #pragma unroll
    for (int f=0; f<4; ++f) bv[f] = *(const half8*)(B + (c0+f*16+lr)*18816 + kb);
    #pragma unroll
    for (int fr=0; fr<4; ++fr)
      #pragma unroll
      for (int fc=0; fc<4; ++fc)
        acc[fr][fc] = __builtin_amdgcn_mfma_f32_16x16x32_f16(av[fr], bv[fc], acc[fr][fc], 0, 0, 0);
    kb += 32;
  }
  float* P = ws + ZGPo + (size_t)ks*393216;
  #pragma unroll
  for (int fr=0; fr<4; ++fr)
    #pragma unroll
    for (int fc=0; fc<4; ++fc)
      #pragma unroll
      for (int r=0; r<4; ++r)
        P[(r0 + fr*16 + kg*4 + r)*512 + c0 + fc*16 + lr] = acc[fr][fc][r];
}

// ---------- split-K reduce + biases ----------
__global__ void k14b_red(const float* bih2, const float* bhh2, float* ws) {
  int i = blockIdx.x*256+threadIdx.x; // 393216 total
  int g = i & 511;
  float s = bih2[g]+bhh2[g];
  #pragma unroll
  for (int ks=0;ks<12;++ks) s += ws[ZGPo + (size_t)ks*393216 + i];
  ws[ZGo + i] = s;
}

// ---------- LSTM2 recurrence: fp16 weights, packed dot2 ----------
__global__ void k15_lstm2(float* ws) {
  int b=blockIdx.x, tid=threadIdx.x; // 512 thr
  __shared__ __align__(16) _Float16 hs[128];
  __shared__ float cc[128], g[512];
  if (tid<128){hs[tid]=(_Float16)0.f; cc[tid]=0.f;}
  const _Float16* wt=(const _Float16*)(ws+WT2Ho); // [16][512][8]
  for (int t=0;t<48;++t){
    __syncthreads();
    int row=b*48+t;
    float acc=ws[ZGo+(size_t)row*512+tid];
    for (int gi=0;gi<16;++gi){
      half8 w = *(const half8*)&wt[(gi*512+tid)*8];
      const half2v* hp=(const half2v*)&hs[gi*8];
      #pragma unroll
      for (int p=0;p<4;++p){ half2v wp={w[2*p],w[2*p+1]}; acc=DOT2(wp,hp[p],acc); }
    }
    g[tid]=acc;
    __syncthreads();
    if (tid<128){
      float ii=sigf(g[tid]);
      float ff=sigf(g[128+tid]);
      float gg=tanhf(g[256+tid]);
      float oo=sigf(g[384+tid]);
      float cn=ff*cc[tid]+ii*gg; cc[tid]=cn;
      float hn=oo*tanhf(cn);
      hs[tid]=(_Float16)hn;
      if (t==47) ws[HTo+b*128+tid]=hn;
    }
  }
}

// ---------- final FC ----------
__global__ void k16_fc(const float* Wfc, const float* bfc, float* out, float* ws) {
  int b=blockIdx.x, tid=threadIdx.x; // 320 thr
  __shared__ float hr[128];
  if (tid<128) hr[tid]=ws[HTo+b*128+tid];
  __syncthreads();
  if (tid<294){
    float acc=bfc[tid];
    const float* wr=Wfc+tid*128;
    for (int k=0;k<128;++k) acc+=hr[k]*wr[k];
    out[b*294+tid]=acc;
  }
}

extern "C" void kernel_launch(void* const* d_in, const int* in_sizes, int n_in,
                              void* d_out, int out_size, void* d_ws, size_t ws_size,
                              hipStream_t stream) {
  const float* X    =(const float*)d_in[0];
  const int*   adj  =(const int*)  d_in[1];
  const float* Wtr  =(const float*)d_in[2];
  const float* btr  =(const float*)d_in[3];
  const float* einw =(const float*)d_in[4];
  const float* einb =(const float*)d_in[5];
  const float* eoutw=(const float*)d_in[6];
  const float* eoutb=(const float*)d_in[7];
  const float* ln1g =(const float*)d_in[8];
  const float* ln1b =(const float*)d_in[9];
  const float* ln2g =(const float*)d_in[10];
  const float* ln2b =(const float*)d_in[11];
  const float* ff1w =(const float*)d_in[12];
  const float* ff1b =(const float*)d_in[13];
  const float* ff2w =(const float*)d_in[14];
  const float* ff2b =(const float*)d_in[15];
  const float* Wih1 =(const float*)d_in[16];
  const float* Whh1 =(const float*)d_in[17];
  const float* bih1 =(const float*)d_in[18];
  const float* bhh1 =(const float*)d_in[19];
  const float* gw1  =(const float*)d_in[20];
  const float* ga1  =(const float*)d_in[21];
  const float* gw2  =(const float*)d_in[22];
  const float* ga2  =(const float*)d_in[23];
  const float* Wsc  =(const float*)d_in[24];
  const float* bsc  =(const float*)d_in[25];
  const float* Wih2 =(const float*)d_in[26];
  const float* Whh2 =(const float*)d_in[27];
  const float* bih2 =(const float*)d_in[28];
  const float* bhh2 =(const float*)d_in[29];
  const float* Wfc  =(const float*)d_in[30];
  const float* bfc  =(const float*)d_in[31];
  float* ws=(float*)d_ws;
  float* out=(float*)d_out;

  k_prep<<<dim3(4931),dim3(256),0,stream>>>(Whh1,Whh2,ff1w,ff2w,Wih1,einw,eoutw,Wtr,gw2,ws);
  k_c12_mask<<<dim3(1),dim3(64),0,stream>>>(gw1,ga1,adj,ws);
  k1_trans<<<dim3(768),dim3(128),0,stream>>>(X,btr,ws);
  k2_qkv<<<dim3(768),dim3(384),0,stream>>>(einb,ws);
  k3_attn<<<dim3(128),dim3(256),0,stream>>>(ws);
  k4_ln1<<<dim3(768),dim3(128),0,stream>>>(eoutb,ln1g,ln1b,ws);
  k5g<<<dim3(96),dim3(256),0,stream>>>(ff1b,ws);
  k6g<<<dim3(6),dim3(256),0,stream>>>(ff2b,ws);
  k6b_ln2<<<dim3(768),dim3(128),0,stream>>>(ln2g,ln2b,ws);
  k7g<<<dim3(57),dim3(256),0,stream>>>(bih1,bhh1,ws);
  k8_lstm1<<<dim3(16),dim3(1024),0,stream>>>(ws);
  k10_gat1<<<dim3(3072),dim3(192),0,stream>>>(ws);
  k11_who<<<dim3(768),dim3(256),0,stream>>>(gw1,ga2,ws);
  k13_gat2<<<dim3(768),dim3(256),0,stream>>>(X,Wsc,bsc,ws);
  kWconv<<<dim3(9408),dim3(256),0,stream>>>(Wih2,ws);
  k14_mfma<<<dim3(288),dim3(256),0,stream>>>(ws);
  k14b_red<<<dim3(1536),dim3(256),0,stream>>>(bih2,bhh2,ws);
  k15_lstm2<<<dim3(16),dim3(512),0,stream>>>(ws);
  k16_fc<<<dim3(16),dim3(320),0,stream>>>(Wfc,bfc,out,ws);
}

// Round 5
// 1069.927 us; speedup vs baseline: 7.7036x; 7.7036x over previous
//
#include <hip/hip_runtime.h>
#include <math.h>

// ---- problem sizes ----
// BS=16, T=48, N=147, IN=294, H=128, AH=8(dh=16), GH=4, DFF=2048, B2=BS*T=768

typedef _Float16 half8 __attribute__((ext_vector_type(8)));
typedef _Float16 half4 __attribute__((ext_vector_type(4)));
typedef _Float16 half2v __attribute__((ext_vector_type(2)));
typedef float f32x4 __attribute__((ext_vector_type(4)));

#if __has_builtin(__builtin_amdgcn_fdot2)
#define DOT2(a,b,c) __builtin_amdgcn_fdot2((a),(b),(c),false)
#else
#define DOT2(a,b,c) ((c) + (float)(a)[0]*(float)(b)[0] + (float)(a)[1]*(float)(b)[1])
#endif

// ---- workspace float offsets ----
// Phase-A buffers alias the Zf region (all dead before Zf is written in k13).
static constexpr size_t Y0o   = 0;         //  98304  [768][128] f32
static constexpr size_t QKVo  = 98304;     // 294912  [768][384] f32
static constexpr size_t ATTOo = 393216;    //  98304
static constexpr size_t Y1o   = 491520;    //  98304  f32 (residual for k6b)
static constexpr size_t Y1Ho  = 589824;    //  49152  fp16 [768][128]
static constexpr size_t FFHo  = 638976;    // 786432  fp16 [768][2048]
static constexpr size_t PREo  = 1425408;   //  98304  f32 [768][128]
static constexpr size_t Y2Ho  = 1523712;   //  49152  fp16 [768][128]
static constexpr size_t XW1o  = 1572864;   // 903168  f32 [768][1176]
static constexpr size_t Y3o   = 2476032;   // 225792  f32 [768][294] (ends 2701824)
static constexpr size_t Zo    = 0;         // fp16 [768][18816] = 7225344 floats (aliases phase A)
static constexpr size_t So    = 7225344;   // 903168  [768][4][147][2]
static constexpr size_t G12o  = 8128512;   // 225792  [768][147][2]
static constexpr size_t WHOTo = 8354304;   // fp16 [768][128][160] = 7864320 floats (ends 16218624)
static constexpr size_t WFo   = 16218624;  // fp16 [512][18816] = 4816896 (ends 21035520)
static constexpr size_t ZGPo  = 21035520;  // f32 [12][768][512] = 4718592 (ends 25754112)
static constexpr size_t ZGo   = 25754112;  // 393216 [768][512]
static constexpr size_t HTo   = 26147328;  //   2048 [16][128]
static constexpr size_t C12o  = 26149376;  //     16
static constexpr size_t WT1Ho = 26149392;  // fp16 [37][1176][8] = 174048 floats
static constexpr size_t WT2Ho = 26323440;  // fp16 [16][512][8]  = 32768
static constexpr size_t FF1Ho = 26356208;  // fp16 [2048][128] = 131072
static constexpr size_t FF2Ho = 26487280;  // fp16 [128][2048] = 131072
static constexpr size_t WIH1Ho= 26618352;  // fp16 [1216][128] = 77824 (rows>=1176 zero)
static constexpr size_t W2To  = 26696176;  // fp16 [128][512] = 32768
static constexpr size_t EINTo = 26728944;  //  49152 [128][384] f32
static constexpr size_t EOUTTo= 26778096;  //  16384 [128][128] f32
static constexpr size_t WTRTo = 26794480;  //  37632 [294][128] f32
static constexpr size_t MASKo = 26832112;  //  u64[441] (896 floats reserved)
// total extent: 26,833,008 floats = 102.4 MiB

__device__ __forceinline__ float eluf(float x){ return x > 0.f ? x : expm1f(x); }
__device__ __forceinline__ float sigf(float x){ return 1.f/(1.f+expf(-x)); }

// ---------- weight transposes / fp16 packs ----------
__global__ void k_prep(const float* Whh1, const float* Whh2, const float* ff1w,
                       const float* ff2w, const float* Wih1, const float* einw,
                       const float* eoutw, const float* wtr, const float* gw2, float* ws) {
  int id = blockIdx.x * 256 + threadIdx.x;
  if (id < 348096) { // WT1H fp16 [37 kg][1176 j][8 k]
    int e=id&7, r=id>>3; int j=r%1176, gi=r/1176; int k=gi*8+e;
    ((_Float16*)(ws+WT1Ho))[id] = (_Float16)((k<294)? Whh1[j*294+k] : 0.f); return; }
  id -= 348096;
  if (id < 65536) { // WT2H fp16 [16][512][8]
    int e=id&7, r=id>>3; int j=r&511, gi=r>>9; int k=gi*8+e;
    ((_Float16*)(ws+WT2Ho))[id] = (_Float16)Whh2[j*128+k]; return; }
  id -= 65536;
  if (id < 262144) { ((_Float16*)(ws+FF1Ho))[id] = (_Float16)ff1w[id]; return; }
  id -= 262144;
  if (id < 262144) { ((_Float16*)(ws+FF2Ho))[id] = (_Float16)ff2w[id]; return; }
  id -= 262144;
  if (id < 155648) { int j=id>>7, k=id&127;
    ((_Float16*)(ws+WIH1Ho))[id] = (_Float16)((j<1176)? Wih1[j*128+k] : 0.f); return; }
  id -= 155648;
  if (id < 65536)  { int h=id>>9, q=id&511;
    ((_Float16*)(ws+W2To))[id] = (_Float16)gw2[q*128+h]; return; }
  id -= 65536;
  if (id < 49152)  { int k=id/384,  j=id-k*384;  ws[EINTo+id] = einw[j*128+k]; return; }
  id -= 49152;
  if (id < 16384)  { int k=id/128,  j=id-k*128;  ws[EOUTTo+id]= eoutw[j*128+k]; return; }
  id -= 16384;
  if (id < 37632)  { int k=id/128,  j=id-k*128;  ws[WTRTo+id] = wtr[j*294+k]; return; }
}

// ---------- GAT scalar precompute + adjacency bitmask ----------
__global__ void k_c12_mask(const float* gw1, const float* ga1, const int* adj, float* ws) {
  int tid = threadIdx.x;
  if (tid < 8) {
    int k = tid>>1, c = tid&1;
    float a=0.f, b=0.f;
    for (int h=0; h<128; ++h) {
      float w = gw1[(k*2+c)*128+h];
      a += w * ga1[k*256+h];
      b += w * ga1[k*256+128+h];
    }
    ws[C12o+tid] = a; ws[C12o+8+tid] = b;
  }
  unsigned long long* msk = (unsigned long long*)(ws + MASKo);
  for (int i = tid; i < 441; i += 64) {
    int r = i/3, w = i-r*3;
    unsigned long long b = 0ull;
    for (int bit=0; bit<64; ++bit) {
      int j = w*64+bit;
      if (j < 147 && adj[r*147+j] > 0) b |= (1ull<<bit);
    }
    msk[i] = b;
  }
}

// ---------- input projection + ELU ----------
__global__ void k1_trans(const float* X, const float* btr, float* ws) {
  int row = blockIdx.x, tid = threadIdx.x; // 128 thr
  __shared__ float xr[294];
  for (int i=tid; i<294; i+=128) xr[i] = X[row*294+i];
  __syncthreads();
  float acc = btr[tid];
  const float* w = ws + WTRTo;
  for (int k=0;k<294;++k) acc += xr[k]*w[k*128+tid];
  ws[Y0o + (size_t)row*128 + tid] = eluf(acc);
}

// ---------- QKV projection ----------
__global__ void k2_qkv(const float* einb, float* ws) {
  int row = blockIdx.x, tid = threadIdx.x; // 384 thr
  __shared__ float yr[128];
  if (tid<128) yr[tid] = ws[Y0o+(size_t)row*128+tid];
  __syncthreads();
  float acc = einb[tid];
  const float* w = ws + EINTo;
  for (int k=0;k<128;++k) acc += yr[k]*w[k*384+tid];
  ws[QKVo + (size_t)row*384 + tid] = acc;
}

// ---------- MHA core ----------
__global__ void k3_attn(float* ws) {
  int bid = blockIdx.x; int bs = bid>>3, a = bid&7; int tid = threadIdx.x; // 256 thr
  __shared__ float q[48][16], kk[48][16], v[48][16], sc[48][49];
  for (int idx=tid; idx<768; idx+=256) {
    int t = idx>>4, d = idx&15;
    const float* base = ws + QKVo + (size_t)(bs*48+t)*384 + a*16 + d;
    q[t][d] = base[0]; kk[t][d] = base[128]; v[t][d] = base[256];
  }
  __syncthreads();
  for (int idx=tid; idx<2304; idx+=256) {
    int i = idx/48, j = idx-i*48;
    float s = 0.f;
    for (int d=0;d<16;++d) s += q[i][d]*kk[j][d];
    sc[i][j] = s*0.25f;
  }
  __syncthreads();
  if (tid < 48) {
    float mx = -INFINITY;
    for (int j=0;j<48;++j) mx = fmaxf(mx, sc[tid][j]);
    float s = 0.f;
    for (int j=0;j<48;++j){ float p = expf(sc[tid][j]-mx); sc[tid][j]=p; s+=p; }
    float inv = 1.f/s;
    for (int j=0;j<48;++j) sc[tid][j]*=inv;
  }
  __syncthreads();
  for (int idx=tid; idx<768; idx+=256) {
    int t = idx>>4, d = idx&15;
    float s=0.f;
    for (int j=0;j<48;++j) s += sc[t][j]*v[j][d];
    ws[ATTOo + (size_t)(bs*48+t)*128 + a*16 + d] = s;
  }
}

// ---------- attn out-proj + residual + LN1 (stores f32 + fp16) ----------
__global__ void k4_ln1(const float* eoutb, const float* g, const float* b, float* ws) {
  int row = blockIdx.x, tid = threadIdx.x; // 128 thr
  __shared__ float orow[128];
  __shared__ float red[128];
  __shared__ float mv[2];
  orow[tid] = ws[ATTOo+(size_t)row*128+tid];
  __syncthreads();
  float acc = eoutb[tid] + ws[Y0o+(size_t)row*128+tid];
  const float* w = ws + EOUTTo;
  for (int k=0;k<128;++k) acc += orow[k]*w[k*128+tid];
  red[tid]=acc; __syncthreads();
  for (int s=64;s>0;s>>=1){ if(tid<s) red[tid]+=red[tid+s]; __syncthreads(); }
  if (tid==0) mv[0]=red[0]*(1.f/128.f);
  __syncthreads();
  float d = acc - mv[0];
  red[tid]=d*d; __syncthreads();
  for (int s=64;s>0;s>>=1){ if(tid<s) red[tid]+=red[tid+s]; __syncthreads(); }
  if (tid==0) mv[1]=red[0]*(1.f/128.f);
  __syncthreads();
  float val = d*rsqrtf(mv[1]+1e-5f)*g[tid]+b[tid];
  ws[Y1o+(size_t)row*128+tid] = val;
  ((_Float16*)(ws+Y1Ho))[(size_t)row*128+tid] = (_Float16)val;
}

// ---------- FFN1 MFMA: FFH = relu(Y1 @ ff1w^T + b1), fp16 out ----------
__global__ void __launch_bounds__(256) k5g(const float* b1, float* ws) {
  int tid=threadIdx.x; int gw=blockIdx.x*4+(tid>>6);
  int l=tid&63, lr=l&15, kg=l>>4;
  int mt=gw>>5, nt=gw&31;
  const _Float16* A=(const _Float16*)(ws+Y1Ho);
  const _Float16* B=(const _Float16*)(ws+FF1Ho);
  _Float16* C=(_Float16*)(ws+FFHo);
  size_t r0=(size_t)mt*64, c0=(size_t)nt*64;
  f32x4 acc[4][4];
  #pragma unroll
  for(int a=0;a<4;++a)
    #pragma unroll
    for(int b=0;b<4;++b) acc[a][b]=(f32x4){0.f,0.f,0.f,0.f};
  #pragma unroll
  for (int s=0;s<4;++s){
    int kb=s*32+kg*8;
    half8 av[4], bv[4];
    #pragma unroll
    for(int f=0;f<4;++f) av[f]=*(const half8*)(A+(r0+f*16+lr)*128+kb);
    #pragma unroll
    for(int f=0;f<4;++f) bv[f]=*(const half8*)(B+(c0+f*16+lr)*128+kb);
    #pragma unroll
    for(int fr=0;fr<4;++fr)
      #pragma unroll
      for(int fc=0;fc<4;++fc)
        acc[fr][fc]=__builtin_amdgcn_mfma_f32_16x16x32_f16(av[fr],bv[fc],acc[fr][fc],0,0,0);
  }
  #pragma unroll
  for(int fr=0;fr<4;++fr)
    #pragma unroll
    for(int fc=0;fc<4;++fc){
      size_t col=c0+fc*16+lr;
      float bb=b1[col];
      #pragma unroll
      for(int r=0;r<4;++r){
        float v=acc[fr][fc][r]+bb; v=fmaxf(v,0.f);
        C[(r0+fr*16+kg*4+r)*2048+col]=(_Float16)v;
      }
    }
}

// ---------- FFN2 MFMA: PRE = FFH @ ff2w^T + b2 (f32 out) ----------
__global__ void __launch_bounds__(256) k6g(const float* b2, float* ws) {
  int tid=threadIdx.x; int gw=blockIdx.x*4+(tid>>6);
  int l=tid&63, lr=l&15, kg=l>>4;
  int mt=gw>>1, nt=gw&1;
  const _Float16* A=(const _Float16*)(ws+FFHo);
  const _Float16* B=(const _Float16*)(ws+FF2Ho);
  float* C=ws+PREo;
  size_t r0=(size_t)mt*64, c0=(size_t)nt*64;
  f32x4 acc[4][4];
  #pragma unroll
  for(int a=0;a<4;++a)
    #pragma unroll
    for(int b=0;b<4;++b) acc[a][b]=(f32x4){0.f,0.f,0.f,0.f};
  for (int s=0;s<64;++s){
    int kb=s*32+kg*8;
    half8 av[4], bv[4];
    #pragma unroll
    for(int f=0;f<4;++f) av[f]=*(const half8*)(A+(r0+f*16+lr)*2048+kb);
    #pragma unroll
    for(int f=0;f<4;++f) bv[f]=*(const half8*)(B+(c0+f*16+lr)*2048+kb);
    #pragma unroll
    for(int fr=0;fr<4;++fr)
      #pragma unroll
      for(int fc=0;fc<4;++fc)
        acc[fr][fc]=__builtin_amdgcn_mfma_f32_16x16x32_f16(av[fr],bv[fc],acc[fr][fc],0,0,0);
  }
  #pragma unroll
  for(int fr=0;fr<4;++fr)
    #pragma unroll
    for(int fc=0;fc<4;++fc){
      size_t col=c0+fc*16+lr;
      float bb=b2[col];
      #pragma unroll
      for(int r=0;r<4;++r)
        C[(r0+fr*16+kg*4+r)*128+col]=acc[fr][fc][r]+bb;
    }
}

// ---------- LN2: Y2H = LN(Y1 + PRE) fp16 ----------
__global__ void k6b_ln2(const float* g, const float* b, float* ws) {
  int row=blockIdx.x, tid=threadIdx.x; // 128 thr
  __shared__ float red[128];
  __shared__ float mv[2];
  float acc = ws[PREo+(size_t)row*128+tid] + ws[Y1o+(size_t)row*128+tid];
  red[tid]=acc; __syncthreads();
  for (int s=64;s>0;s>>=1){ if(tid<s) red[tid]+=red[tid+s]; __syncthreads(); }
  if (tid==0) mv[0]=red[0]*(1.f/128.f);
  __syncthreads();
  float d = acc - mv[0];
  red[tid]=d*d; __syncthreads();
  for (int s=64;s>0;s>>=1){ if(tid<s) red[tid]+=red[tid+s]; __syncthreads(); }
  if (tid==0) mv[1]=red[0]*(1.f/128.f);
  __syncthreads();
  float val = d*rsqrtf(mv[1]+1e-5f)*g[tid]+b[tid];
  ((_Float16*)(ws+Y2Ho))[(size_t)row*128+tid] = (_Float16)val;
}

// ---------- LSTM1 input proj MFMA: XW1 = Y2 @ Wih1^T + biases (f32) ----------
__global__ void __launch_bounds__(256) k7g(const float* bih1, const float* bhh1, float* ws) {
  int tid=threadIdx.x; int gw=blockIdx.x*4+(tid>>6);
  int l=tid&63, lr=l&15, kg=l>>4;
  int mt=gw/19, nt=gw-mt*19;
  const _Float16* A=(const _Float16*)(ws+Y2Ho);
  const _Float16* B=(const _Float16*)(ws+WIH1Ho);
  float* C=ws+XW1o;
  size_t r0=(size_t)mt*64, c0=(size_t)nt*64;
  f32x4 acc[4][4];
  #pragma unroll
  for(int a=0;a<4;++a)
    #pragma unroll
    for(int b=0;b<4;++b) acc[a][b]=(f32x4){0.f,0.f,0.f,0.f};
  #pragma unroll
  for (int s=0;s<4;++s){
    int kb=s*32+kg*8;
    half8 av[4], bv[4];
    #pragma unroll
    for(int f=0;f<4;++f) av[f]=*(const half8*)(A+(r0+f*16+lr)*128+kb);
    #pragma unroll
    for(int f=0;f<4;++f) bv[f]=*(const half8*)(B+(c0+f*16+lr)*128+kb);
    #pragma unroll
    for(int fr=0;fr<4;++fr)
      #pragma unroll
      for(int fc=0;fc<4;++fc)
        acc[fr][fc]=__builtin_amdgcn_mfma_f32_16x16x32_f16(av[fr],bv[fc],acc[fr][fc],0,0,0);
  }
  #pragma unroll
  for(int fr=0;fr<4;++fr)
    #pragma unroll
    for(int fc=0;fc<4;++fc){
      size_t col=c0+fc*16+lr;
      if (col<1176){
        float bb=bih1[col]+bhh1[col];
        #pragma unroll
        for(int r=0;r<4;++r)
          C[(r0+fr*16+kg*4+r)*1176+col]=acc[fr][fc][r]+bb;
      }
    }
}

// ---------- LSTM1 recurrence: fp16 weights, packed dot2 ----------
__global__ void __launch_bounds__(1024) k8_lstm1(float* ws) {
  int b = blockIdx.x, tid = threadIdx.x; // 1024 thr
  __shared__ __align__(16) _Float16 hs[296];
  __shared__ float cc[294], g[1176];
  if (tid < 296) hs[tid] = (_Float16)0.f;
  if (tid < 294) cc[tid] = 0.f;
  const _Float16* wt = (const _Float16*)(ws + WT1Ho); // [37][1176][8]
  for (int t=0;t<48;++t) {
    __syncthreads();
    int row = b*48+t;
    for (int jj=tid; jj<1176; jj+=1024) {
      float acc = ws[XW1o+(size_t)row*1176+jj];
      for (int gi=0; gi<37; ++gi) {
        half8 w = *(const half8*)&wt[(gi*1176+jj)*8];
        const half2v* hp = (const half2v*)&hs[gi*8];
        #pragma unroll
        for (int p=0;p<4;++p) {
          half2v wp = {w[2*p], w[2*p+1]};
          acc = DOT2(wp, hp[p], acc);
        }
      }
      g[jj]=acc;
    }
    __syncthreads();
    if (tid<294) {
      float ii=sigf(g[tid]);
      float ff=sigf(g[294+tid]);
      float gg=tanhf(g[588+tid]);
      float oo=sigf(g[882+tid]);
      float cn = ff*cc[tid]+ii*gg;
      cc[tid]=cn;
      float hn = oo*tanhf(cn);
      hs[tid] = (_Float16)hn;
      ws[Y3o+(size_t)row*294+tid]=hn;
    }
  }
}

// ---------- GAT layer 1: masked softmax + rank-2 aggregation ----------
__global__ void k10_gat1(float* ws) {
  int bid=blockIdx.x; int m=bid>>2, k=bid&3; int tid=threadIdx.x; // 192 thr
  __shared__ float x0[147],x1[147],f1[147],f2[147];
  __shared__ unsigned long long msk[441];
  for (int i=tid;i<294;i+=192){
    int n=i>>1,cc=i&1;
    float v=ws[Y3o + (size_t)n*1536 + m*2 + cc];
    if(cc==0)x0[n]=v; else x1[n]=v;
  }
  const unsigned long long* gm = (const unsigned long long*)(ws+MASKo);
  for (int i=tid;i<441;i+=192) msk[i]=gm[i];
  __syncthreads();
  float c10=ws[C12o+k*2], c11=ws[C12o+k*2+1], c20=ws[C12o+8+k*2], c21=ws[C12o+8+k*2+1];
  for (int i=tid;i<147;i+=192){ f1[i]=x0[i]*c10+x1[i]*c11; f2[i]=x0[i]*c20+x1[i]*c21; }
  __syncthreads();
  for (int i=tid;i<147;i+=192) {
    float fi=f1[i];
    float mx=-INFINITY;
    for (int j=0;j<147;++j){
      float e=fi+f2[j]; e = e>0.f?e:0.1f*e;
      bool mk = (msk[i*3+(j>>6)]>>(j&63))&1ull;
      mx = fmaxf(mx, mk? e : -9e15f);
    }
    float s=0.f,a0=0.f,a1=0.f;
    for (int j=0;j<147;++j){
      float e=fi+f2[j]; e = e>0.f?e:0.1f*e;
      bool mk=(msk[i*3+(j>>6)]>>(j&63))&1ull;
      float p = expf((mk? e: -9e15f)-mx);
      s+=p; a0+=p*x0[j]; a1+=p*x1[j];
    }
    float inv=1.f/s;
    size_t o = So + ((size_t)(m*4+k)*147+i)*2;
    ws[o]=a0*inv; ws[o+1]=a1*inv;
  }
}

// ---------- GAT layer 2 GEMM (MFMA) + fused g1/g2: whoT(fp16,[m][col][160]) = (elu(h1)@W2)^T ----------
__global__ void __launch_bounds__(256) k11_who(const float* gw1, const float* ga2, float* ws) {
  int m=blockIdx.x, tid=threadIdx.x;
  int w=tid>>6, l=tid&63, lr=l&15, kg=l>>4;
  __shared__ float s0s[4][148], s1s[4][148];
  __shared__ float w1s[1024];
  __shared__ float a2s[256];
  __shared__ _Float16 h1t[160*32];
  __shared__ float g1s[160], g2s[160];
  for (int idx=tid; idx<588; idx+=256){
    int k=idx/147, i=idx-k*147;
    size_t o=So+((size_t)(m*4+k)*147+i)*2; s0s[k][i]=ws[o]; s1s[k][i]=ws[o+1];
  }
  for (int idx=tid; idx<1024; idx+=256) w1s[idx]=gw1[idx];
  for (int idx=tid; idx<256; idx+=256) a2s[idx]=ga2[idx];
  if (tid<160){ g1s[tid]=0.f; g2s[tid]=0.f; }
  f32x4 acc[10][2];
  #pragma unroll
  for(int a=0;a<10;++a){ acc[a][0]=(f32x4){0.f,0.f,0.f,0.f}; acc[a][1]=(f32x4){0.f,0.f,0.f,0.f}; }
  const _Float16* W2T = (const _Float16*)(ws+W2To);
  for (int q0=0;q0<512;q0+=32){
    __syncthreads();
    for (int idx=tid; idx<5120; idx+=256){
      int i=idx>>5, kk=idx&31;
      _Float16 hv=(_Float16)0.f;
      if (i<147){
        int q=q0+kk, k=q>>7, hp=q&127;
        float v=s0s[k][i]*w1s[k*256+hp]+s1s[k][i]*w1s[k*256+128+hp];
        hv=(_Float16)eluf(v);
      }
      h1t[idx]=hv;
    }
    __syncthreads();
    half8 bv0=*(const half8*)(W2T+(size_t)(w*32+lr)*512+q0+kg*8);
    half8 bv1=*(const half8*)(W2T+(size_t)(w*32+16+lr)*512+q0+kg*8);
    #pragma unroll
    for (int rf=0;rf<10;++rf){
      half8 av=*(const half8*)&h1t[(rf*16+lr)*32+kg*8];
      acc[rf][0]=__builtin_amdgcn_mfma_f32_16x16x32_f16(av,bv0,acc[rf][0],0,0,0);
      acc[rf][1]=__builtin_amdgcn_mfma_f32_16x16x32_f16(av,bv1,acc[rf][1],0,0,0);
    }
  }
  // store transposed: whoT[m][col][row], rows 147..159 are zeros (h1t zero-padded)
  _Float16* whoT=(_Float16*)(ws+WHOTo);
  #pragma unroll
  for (int rf=0;rf<10;++rf)
    #pragma unroll
    for (int cf=0;cf<2;++cf){
      int col=w*32+cf*16+lr;
      half4 hv = {(_Float16)acc[rf][cf][0],(_Float16)acc[rf][cf][1],
                  (_Float16)acc[rf][cf][2],(_Float16)acc[rf][cf][3]};
      *(half4*)&whoT[((size_t)m*128+col)*160 + rf*16+kg*4] = hv;
      #pragma unroll
      for (int r=0;r<4;++r){
        int row=rf*16+kg*4+r;
        float v=acc[rf][cf][r];
        bool ok=row<147;
        float p1=ok? v*a2s[col]:0.f;
        float p2=ok? v*a2s[128+col]:0.f;
        p1+=__shfl_xor(p1,1); p1+=__shfl_xor(p1,2); p1+=__shfl_xor(p1,4); p1+=__shfl_xor(p1,8);
        p2+=__shfl_xor(p2,1); p2+=__shfl_xor(p2,2); p2+=__shfl_xor(p2,4); p2+=__shfl_xor(p2,8);
        if (ok && lr==0){ atomicAdd(&g1s[row],p1); atomicAdd(&g2s[row],p2); }
      }
    }
  __syncthreads();
  for (int i=tid;i<147;i+=256){
    ws[G12o+((size_t)m*147+i)*2]=g1s[i];
    ws[G12o+((size_t)m*147+i)*2+1]=g2s[i];
  }
}

// ---------- GAT layer 2: softmax(fp16 LDS) + MFMA PV + elu + sc shortcut + scatter to Zf ----------
__global__ void __launch_bounds__(256) k13_gat2(const float* X, const float* Wsc, const float* bsc, float* ws) {
  int m=blockIdx.x, tid=threadIdx.x; // 256 thr, 4 waves
  int w=tid>>6, l=tid&63, lr=l&15, kg=l>>4;
  __shared__ _Float16 att_h[80][168];   // row stride 336B: 16B-aligned, ~2-way banks
  __shared__ float g1s[147], g2s[147];
  __shared__ float wscs[256], bscs[128];
  __shared__ unsigned long long msk[441];
  _Float16* zf=(_Float16*)(ws+Zo);
  const _Float16* whoT=(const _Float16*)(ws+WHOTo);
  for (int i=tid;i<147;i+=256){ size_t o=G12o+((size_t)m*147+i)*2; g1s[i]=ws[o]; g2s[i]=ws[o+1]; }
  wscs[tid]=Wsc[tid];
  if (tid<128) bscs[tid]=bsc[tid];
  const unsigned long long* gm=(const unsigned long long*)(ws+MASKo);
  for (int i=tid;i<441;i+=256) msk[i]=gm[i];
  __syncthreads();
  for (int p=0;p<2;++p){
    int i0=p*74, cnt=p?73:74;
    // ---- masked softmax -> fp16 att_h (two-pass, exp recomputed; pads zeroed) ----
    for (int r=tid;r<80;r+=256){
      if (r<cnt){
        int i=i0+r; float gi=g1s[i];
        float mx=-INFINITY;
        for (int j=0;j<147;++j){
          float e=gi+g2s[j]; e=e>0.f?e:0.1f*e;
          bool mk=(msk[i*3+(j>>6)]>>(j&63))&1ull;
          mx=fmaxf(mx,mk?e:-9e15f);
        }
        float s=0.f;
        for (int j=0;j<147;++j){
          float e=gi+g2s[j]; e=e>0.f?e:0.1f*e;
          bool mk=(msk[i*3+(j>>6)]>>(j&63))&1ull;
          s+=expf((mk?e:-9e15f)-mx);
        }
        float inv=1.f/s;
        for (int j=0;j<147;++j){
          float e=gi+g2s[j]; e=e>0.f?e:0.1f*e;
          bool mk=(msk[i*3+(j>>6)]>>(j&63))&1ull;
          att_h[r][j]=(_Float16)(expf((mk?e:-9e15f)-mx)*inv);
        }
        for (int j=147;j<168;++j) att_h[r][j]=(_Float16)0.f;
      } else {
        for (int j=0;j<168;++j) att_h[r][j]=(_Float16)0.f;
      }
    }
    __syncthreads();
    // ---- PV via MFMA: A = att_h (LDS), B = whoT (global, L2-resident) ----
    f32x4 acc[5][2];
    #pragma unroll
    for (int a=0;a<5;++a){ acc[a][0]=(f32x4){0.f,0.f,0.f,0.f}; acc[a][1]=(f32x4){0.f,0.f,0.f,0.f}; }
    int c0=w*32+lr, c1=w*32+16+lr;
    #pragma unroll
    for (int s=0;s<5;++s){
      int j0=s*32;
      half8 bv0=*(const half8*)&whoT[((size_t)m*128+c0)*160+j0+kg*8];
      half8 bv1=*(const half8*)&whoT[((size_t)m*128+c1)*160+j0+kg*8];
      #pragma unroll
      for (int rf=0;rf<5;++rf){
        half8 av=*(const half8*)&att_h[rf*16+lr][j0+kg*8];
        acc[rf][0]=__builtin_amdgcn_mfma_f32_16x16x32_f16(av,bv0,acc[rf][0],0,0,0);
        acc[rf][1]=__builtin_amdgcn_mfma_f32_16x16x32_f16(av,bv1,acc[rf][1],0,0,0);
      }
    }
    __syncthreads(); // att_h reads done before next phase overwrites
    // ---- epilogue: elu(pv) + elu(sc), scatter to Zf ----
    #pragma unroll
    for (int rf=0;rf<5;++rf)
      #pragma unroll
      for (int r_=0;r_<4;++r_){
        int row=rf*16+kg*4+r_;
        if (row<cnt){
          int i=i0+row;
          int gbase=i*98304+m*128;
          int bs=gbase/903168; int r2=gbase-bs*903168;
          int t=r2/18816; int qb=r2-t*18816;
          int nn=qb>>7;
          const float* xr=X+(size_t)(bs*48+t)*294+nn*2;
          float x0=xr[0],x1=xr[1];
          size_t zb=(size_t)(bs*48+t)*18816+qb;
          #pragma unroll
          for (int cf=0;cf<2;++cf){
            int col=w*32+cf*16+lr;
            float pv=acc[rf][cf][r_];
            float sv=x0*wscs[col*2]+x1*wscs[col*2+1]+bscs[col];
            zf[zb+col]=(_Float16)(eluf(pv)+eluf(sv));
          }
        }
      }
  }
}

// ---------- Wih2 -> fp16 ----------
__global__ void kWconv(const float* Wih2, float* ws) {
  size_t i = ((size_t)blockIdx.x*256 + threadIdx.x)*4;
  _Float16* wf = (_Float16*)(ws + WFo);
  float4 v = *(const float4*)&Wih2[i];
  half4 h = {(_Float16)v.x, (_Float16)v.y, (_Float16)v.z, (_Float16)v.w};
  *(half4*)&wf[i] = h;
}

// ---------- Zg = Zf @ WfT : fp16 MFMA, per-wave 64x64 tiles, split-K=12 ----------
__global__ void __launch_bounds__(256) k14_mfma(float* ws) {
  const int tid = threadIdx.x;
  const int gw = blockIdx.x*4 + (tid>>6);     // global wave id, 0..1151
  const int l = tid & 63, lr = l & 15, kg = l >> 4;
  const int ks = gw / 96;                      // K-split 0..11
  const int tile = gw - ks*96;
  const int mt = tile >> 3, nt = tile & 7;     // 12 x 8 tiles of 64x64
  const size_t r0 = (size_t)mt*64, c0 = (size_t)nt*64;
  const _Float16* A = (const _Float16*)(ws + Zo);   // [768][18816]
  const _Float16* B = (const _Float16*)(ws + WFo);  // [512][18816]
  f32x4 acc[4][4];
  #pragma unroll
  for (int a=0;a<4;++a)
    #pragma unroll
    for (int b=0;b<4;++b) acc[a][b] = (f32x4){0.f,0.f,0.f,0.f};
  size_t kb = (size_t)ks*1568 + kg*8;
  for (int s=0; s<49; ++s) {
    half8 av[4], bv[4];
    #pragma unroll
    for (int f=0; f<4; ++f) av[f] = *(const half8*)(A + (r0+f*16+lr)*18816 + kb);
    #pragma unroll
    for (int f=0; f<4; ++f) bv[f] = *(const half8*)(B + (c0+f*16+lr)*18816 + kb);
    #pragma unroll
    for (int fr=0; fr<4; ++fr)
      #pragma unroll
      for (int fc=0; fc<4; ++fc)
        acc[fr][fc] = __builtin_amdgcn_mfma_f32_16x16x32_f16(av[fr], bv[fc], acc[fr][fc], 0, 0, 0);
    kb += 32;
  }
  float* P = ws + ZGPo + (size_t)ks*393216;
  #pragma unroll
  for (int fr=0; fr<4; ++fr)
    #pragma unroll
    for (int fc=0; fc<4; ++fc)
      #pragma unroll
      for (int r=0; r<4; ++r)
        P[(r0 + fr*16 + kg*4 + r)*512 + c0 + fc*16 + lr] = acc[fr][fc][r];
}

// ---------- split-K reduce + biases ----------
__global__ void k14b_red(const float* bih2, const float* bhh2, float* ws) {
  int i = blockIdx.x*256+threadIdx.x; // 393216 total
  int g = i & 511;
  float s = bih2[g]+bhh2[g];
  #pragma unroll
  for (int ks=0;ks<12;++ks) s += ws[ZGPo + (size_t)ks*393216 + i];
  ws[ZGo + i] = s;
}

// ---------- LSTM2 recurrence: fp16 weights, packed dot2 ----------
__global__ void k15_lstm2(float* ws) {
  int b=blockIdx.x, tid=threadIdx.x; // 512 thr
  __shared__ __align__(16) _Float16 hs[128];
  __shared__ float cc[128], g[512];
  if (tid<128){hs[tid]=(_Float16)0.f; cc[tid]=0.f;}
  const _Float16* wt=(const _Float16*)(ws+WT2Ho); // [16][512][8]
  for (int t=0;t<48;++t){
    __syncthreads();
    int row=b*48+t;
    float acc=ws[ZGo+(size_t)row*512+tid];
    for (int gi=0;gi<16;++gi){
      half8 w = *(const half8*)&wt[(gi*512+tid)*8];
      const half2v* hp=(const half2v*)&hs[gi*8];
      #pragma unroll
      for (int p=0;p<4;++p){ half2v wp={w[2*p],w[2*p+1]}; acc=DOT2(wp,hp[p],acc); }
    }
    g[tid]=acc;
    __syncthreads();
    if (tid<128){
      float ii=sigf(g[tid]);
      float ff=sigf(g[128+tid]);
      float gg=tanhf(g[256+tid]);
      float oo=sigf(g[384+tid]);
      float cn=ff*cc[tid]+ii*gg; cc[tid]=cn;
      float hn=oo*tanhf(cn);
      hs[tid]=(_Float16)hn;
      if (t==47) ws[HTo+b*128+tid]=hn;
    }
  }
}

// ---------- final FC ----------
__global__ void k16_fc(const float* Wfc, const float* bfc, float* out, float* ws) {
  int b=blockIdx.x, tid=threadIdx.x; // 320 thr
  __shared__ float hr[128];
  if (tid<128) hr[tid]=ws[HTo+b*128+tid];
  __syncthreads();
  if (tid<294){
    float acc=bfc[tid];
    const float* wr=Wfc+tid*128;
    for (int k=0;k<128;++k) acc+=hr[k]*wr[k];
    out[b*294+tid]=acc;
  }
}

extern "C" void kernel_launch(void* const* d_in, const int* in_sizes, int n_in,
                              void* d_out, int out_size, void* d_ws, size_t ws_size,
                              hipStream_t stream) {
  const float* X    =(const float*)d_in[0];
  const int*   adj  =(const int*)  d_in[1];
  const float* Wtr  =(const float*)d_in[2];
  const float* btr  =(const float*)d_in[3];
  const float* einw =(const float*)d_in[4];
  const float* einb =(const float*)d_in[5];
  const float* eoutw=(const float*)d_in[6];
  const float* eoutb=(const float*)d_in[7];
  const float* ln1g =(const float*)d_in[8];
  const float* ln1b =(const float*)d_in[9];
  const float* ln2g =(const float*)d_in[10];
  const float* ln2b =(const float*)d_in[11];
  const float* ff1w =(const float*)d_in[12];
  const float* ff1b =(const float*)d_in[13];
  const float* ff2w =(const float*)d_in[14];
  const float* ff2b =(const float*)d_in[15];
  const float* Wih1 =(const float*)d_in[16];
  const float* Whh1 =(const float*)d_in[17];
  const float* bih1 =(const float*)d_in[18];
  const float* bhh1 =(const float*)d_in[19];
  const float* gw1  =(const float*)d_in[20];
  const float* ga1  =(const float*)d_in[21];
  const float* gw2  =(const float*)d_in[22];
  const float* ga2  =(const float*)d_in[23];
  const float* Wsc  =(const float*)d_in[24];
  const float* bsc  =(const float*)d_in[25];
  const float* Wih2 =(const float*)d_in[26];
  const float* Whh2 =(const float*)d_in[27];
  const float* bih2 =(const float*)d_in[28];
  const float* bhh2 =(const float*)d_in[29];
  const float* Wfc  =(const float*)d_in[30];
  const float* bfc  =(const float*)d_in[31];
  float* ws=(float*)d_ws;
  float* out=(float*)d_out;

  k_prep<<<dim3(4931),dim3(256),0,stream>>>(Whh1,Whh2,ff1w,ff2w,Wih1,einw,eoutw,Wtr,gw2,ws);
  k_c12_mask<<<dim3(1),dim3(64),0,stream>>>(gw1,ga1,adj,ws);
  k1_trans<<<dim3(768),dim3(128),0,stream>>>(X,btr,ws);
  k2_qkv<<<dim3(768),dim3(384),0,stream>>>(einb,ws);
  k3_attn<<<dim3(128),dim3(256),0,stream>>>(ws);
  k4_ln1<<<dim3(768),dim3(128),0,stream>>>(eoutb,ln1g,ln1b,ws);
  k5g<<<dim3(96),dim3(256),0,stream>>>(ff1b,ws);
  k6g<<<dim3(6),dim3(256),0,stream>>>(ff2b,ws);
  k6b_ln2<<<dim3(768),dim3(128),0,stream>>>(ln2g,ln2b,ws);
  k7g<<<dim3(57),dim3(256),0,stream>>>(bih1,bhh1,ws);
  k8_lstm1<<<dim3(16),dim3(1024),0,stream>>>(ws);
  k10_gat1<<<dim3(3072),dim3(192),0,stream>>>(ws);
  k11_who<<<dim3(768),dim3(256),0,stream>>>(gw1,ga2,ws);
  k13_gat2<<<dim3(768),dim3(256),0,stream>>>(X,Wsc,bsc,ws);
  kWconv<<<dim3(9408),dim3(256),0,stream>>>(Wih2,ws);
  k14_mfma<<<dim3(288),dim3(256),0,stream>>>(ws);
  k14b_red<<<dim3(1536),dim3(256),0,stream>>>(bih2,bhh2,ws);
  k15_lstm2<<<dim3(16),dim3(512),0,stream>>>(ws);
  k16_fc<<<dim3(16),dim3(320),0,stream>>>(Wfc,bfc,out,ws);
}